// Round 10
// baseline (324.543 us; speedup 1.0000x reference)
//
#include <hip/hip_runtime.h>

// HierarchicalGraphSAGE bf16-MFMA version, R10.
// N=50000, E=800000, D=128, OUT=64, G=64.
//
//  R10 vs R9: launch-count + fusion package (23 -> 14 dispatches):
//   - CSR node stage (hist2 + 3 scans + fillfine) -> ONE k_fillfine2 per
//     bucket: bucket's CSR base == its binned-edge base (bbase[b]), so
//     hist/scan/starts/scatter are all bucket-local in LDS.
//   - matrix scan: k_mrowscan (per-bucket row scan + total) + k_scan2b
//     (single-block scan of 391 totals); offset add folded into binscatter.
//   - fp8-h write fused into k_sage epilogue (kills 2x k_cast8).
//   - pool fused into layer-3 k_sage (LDS 8x128 group buf + atomic flush);
//     counts via binary search in k_final (gcnt gone).
//   - x-cast + w-cast merged; single memset.

typedef __bf16 bf16x8 __attribute__((ext_vector_type(8)));
typedef float f32x4 __attribute__((ext_vector_type(4)));
typedef float f32x2 __attribute__((ext_vector_type(2)));

#define BINB 160          // binning blocks
#define NBMAX 512         // max buckets (N <= 65536)

static __device__ __forceinline__ float bf2f(unsigned short u) {
    union { unsigned u; float f; } c; c.u = (unsigned)u << 16; return c.f;
}
static __device__ __forceinline__ unsigned short f2bf(float f) {
    unsigned u = __builtin_bit_cast(unsigned, f);
    return (unsigned short)((u + 0x7fffu + ((u >> 16) & 1u)) >> 16);
}
static __device__ __forceinline__ uint2 pk8_fp8(const float* f) {
    int lo = 0, hi = 0;
    lo = __builtin_amdgcn_cvt_pk_fp8_f32(f[0], f[1], lo, false);
    lo = __builtin_amdgcn_cvt_pk_fp8_f32(f[2], f[3], lo, true);
    hi = __builtin_amdgcn_cvt_pk_fp8_f32(f[4], f[5], hi, false);
    hi = __builtin_amdgcn_cvt_pk_fp8_f32(f[6], f[7], hi, true);
    return make_uint2((unsigned)lo, (unsigned)hi);
}
static __device__ __forceinline__ unsigned char f2fp8(float v) {
    return (unsigned char)(__builtin_amdgcn_cvt_pk_fp8_f32(v, v, 0, false) & 0xff);
}

// ---------------- bucket counting sort ----------------
__global__ __launch_bounds__(256) void k_bincount(
    const int* __restrict__ dst, int* __restrict__ cnt_mat, int E, int nb, int epb)
{
    __shared__ int lc[NBMAX];
    for (int i = threadIdx.x; i < nb; i += 256) lc[i] = 0;
    __syncthreads();
    int b0 = blockIdx.x * epb;
    int b1 = min(b0 + epb, E);
    for (int i = b0 + threadIdx.x; i < b1; i += 256)
        atomicAdd(&lc[dst[i] >> 7], 1);
    __syncthreads();
    for (int i = threadIdx.x; i < nb; i += 256)
        cnt_mat[i * BINB + blockIdx.x] = lc[i];
}

// Per-bucket: exclusive scan of its BINB-entry row; emit bucket total.
__global__ __launch_bounds__(256) void k_mrowscan(
    const int* __restrict__ cnt_mat, int* __restrict__ rowloc, int* __restrict__ btot)
{
    __shared__ int s[256];
    int b = blockIdx.x;
    int t = threadIdx.x;
    int v = (t < BINB) ? cnt_mat[b * BINB + t] : 0;
    s[t] = v;
    __syncthreads();
#pragma unroll
    for (int off = 1; off < 256; off <<= 1) {
        int u = (t >= off) ? s[t - off] : 0;
        __syncthreads();
        s[t] += u;
        __syncthreads();
    }
    if (t < BINB) rowloc[b * BINB + t] = s[t] - v;
    if (t == 255) btot[b] = s[255];
}

// Single block: exclusive scan of nb (<=1024) bucket totals -> bbase; total -> *total_out.
__global__ __launch_bounds__(256) void k_scan2b(
    const int* __restrict__ btot, int* __restrict__ bbase, int nb, int* __restrict__ total_out)
{
    __shared__ int s[256];
    int t = threadIdx.x;
    int per = (nb + 255) / 256;
    int s0 = t * per, e0 = min(s0 + per, nb);
    int sum = 0;
    for (int i = s0; i < e0; ++i) sum += btot[i];
    s[t] = sum;
    __syncthreads();
#pragma unroll
    for (int off = 1; off < 256; off <<= 1) {
        int u = (t >= off) ? s[t - off] : 0;
        __syncthreads();
        s[t] += u;
        __syncthreads();
    }
    int run = s[t] - sum;
    for (int i = s0; i < e0; ++i) { bbase[i] = run; run += btot[i]; }
    if (t == 255) *total_out = s[255];
}

__global__ __launch_bounds__(256) void k_binscatter(
    const int* __restrict__ ei, const int* __restrict__ rowloc, const int* __restrict__ bbase,
    unsigned* __restrict__ binned, int E, int nb, int epb)
{
    __shared__ int lofs[NBMAX];
    __shared__ int lcnt[NBMAX];
    for (int i = threadIdx.x; i < nb; i += 256) {
        lofs[i] = rowloc[i * BINB + blockIdx.x] + bbase[i];
        lcnt[i] = 0;
    }
    __syncthreads();
    int b0 = blockIdx.x * epb;
    int b1 = min(b0 + epb, E);
    for (int i = b0 + threadIdx.x; i < b1; i += 256) {
        int s = ei[i];
        int d = ei[E + i];
        int b = d >> 7;
        int r = atomicAdd(&lcnt[b], 1);
        binned[lofs[b] + r] = (unsigned)s | ((unsigned)(d & 127) << 16);
    }
}

// Per-bucket: node hist -> local scan -> starts[] -> fine scatter. All in LDS.
// Bucket b's CSR range is [bbase[b], be): identical to its binned range.
__global__ __launch_bounds__(256) void k_fillfine2(
    const unsigned* __restrict__ binned, const int* __restrict__ bbase,
    int* __restrict__ starts, unsigned short* __restrict__ csr_src,
    int E, int nb, int n)
{
    __shared__ int lc[128];
    __shared__ int lpos[128];
    int b = blockIdx.x;
    int t = threadIdx.x;
    int node0 = b << 7;
    int bs = bbase[b];
    int be = (b == nb - 1) ? E : bbase[b + 1];
    if (t < 128) lc[t] = 0;
    __syncthreads();
    // pass 1: node histogram
    for (int i = bs + t; i < be; i += 256)
        atomicAdd(&lc[(binned[i] >> 16) & 127], 1);
    __syncthreads();
    // local exclusive scan of 128 counts (in lpos as scratch)
    int v = (t < 128) ? lc[t] : 0;
    if (t < 128) lpos[t] = v;
    __syncthreads();
#pragma unroll
    for (int off = 1; off < 128; off <<= 1) {
        int u = (t >= off && t < 128) ? lpos[t - off] : 0;
        __syncthreads();
        if (t < 128) lpos[t] += u;
        __syncthreads();
    }
    int excl = (t < 128) ? (lpos[t] - v) : 0;
    __syncthreads();
    if (t < 128) {
        int node = node0 + t;
        if (node < n) starts[node] = bs + excl;
        lpos[t] = bs + excl;   // slot counters
    }
    if (b == nb - 1 && t == 0) starts[n] = E;
    __syncthreads();
    // pass 2: fine scatter
    for (int i = bs + t; i < be; i += 256) {
        unsigned e = binned[i];
        int slot = atomicAdd(&lpos[(e >> 16) & 127], 1);
        csr_src[slot] = (unsigned short)(e & 0xffffu);
    }
}

// ---------------- casts (x -> bf16+fp8, weights -> hi/lo), one launch ------
__global__ __launch_bounds__(256) void k_cast_all(
    const float* __restrict__ x, unsigned short* __restrict__ xb,
    unsigned char* __restrict__ x8, int n8, int nxblk,
    const float* __restrict__ W1l, const float* __restrict__ W1r,
    const float* __restrict__ W2l, const float* __restrict__ W2r,
    const float* __restrict__ W3l, const float* __restrict__ W3r,
    unsigned short* __restrict__ Whi, unsigned short* __restrict__ Wlo)
{
    int bid = blockIdx.x;
    if (bid < nxblk) {
        int i = bid * 256 + threadIdx.x;
        if (i >= n8) return;
        float f[8];
        *(float4*)(f + 0) = *(const float4*)(x + (size_t)i * 8);
        *(float4*)(f + 4) = *(const float4*)(x + (size_t)i * 8 + 4);
        ushort4 oa, ob;
        oa.x = f2bf(f[0]); oa.y = f2bf(f[1]); oa.z = f2bf(f[2]); oa.w = f2bf(f[3]);
        ob.x = f2bf(f[4]); ob.y = f2bf(f[5]); ob.z = f2bf(f[6]); ob.w = f2bf(f[7]);
        *(ushort4*)(xb + (size_t)i * 8) = oa;
        *(ushort4*)(xb + (size_t)i * 8 + 4) = ob;
        *(uint2*)(x8 + (size_t)i * 8) = pk8_fp8(f);
    } else {
        int wb = bid - nxblk;          // 0..383
        int layer = wb >> 7;
        int row = wb & 127;
        int col = threadIdx.x;
        const float* Wl = (layer == 0) ? W1l : (layer == 1) ? W2l : W3l;
        const float* Wr = (layer == 0) ? W1r : (layer == 1) ? W2r : W3r;
        float w = (col < 128) ? Wl[row * 128 + col] : Wr[row * 128 + col - 128];
        unsigned short hi = f2bf(w);
        float lo = w - bf2f(hi);
        size_t o = (size_t)layer * 32768 + row * 256 + col;
        Whi[o] = hi;
        Wlo[o] = f2bf(lo);
    }
}

// ---------------- aggregate: wave/node, fp8 rows, 4 edges per wave load ----
__global__ __launch_bounds__(256) void k_agg(
    const unsigned char* __restrict__ h8, const int* __restrict__ starts,
    const unsigned short* __restrict__ csr, unsigned short* __restrict__ aggb, int n)
{
    int node = blockIdx.x * 4 + (threadIdx.x >> 6);
    int lane = threadIdx.x & 63;
    if (node >= n) return;
    int eg = lane >> 4;
    int fb = lane & 15;
    const unsigned char* hrow = h8 + fb * 8;
    int s = starts[node], e = starts[node + 1];
    float a0 = 0.f, a1 = 0.f, a2 = 0.f, a3 = 0.f,
          a4 = 0.f, a5 = 0.f, a6 = 0.f, a7 = 0.f;

#define ACC8(v)                                                         \
    do {                                                                \
        f32x2 p0 = __builtin_amdgcn_cvt_pk_f32_fp8((v).x, false);       \
        f32x2 p1 = __builtin_amdgcn_cvt_pk_f32_fp8((v).x, true);        \
        f32x2 p2 = __builtin_amdgcn_cvt_pk_f32_fp8((v).y, false);       \
        f32x2 p3 = __builtin_amdgcn_cvt_pk_f32_fp8((v).y, true);        \
        a0 += p0.x; a1 += p0.y; a2 += p1.x; a3 += p1.y;                 \
        a4 += p2.x; a5 += p2.y; a6 += p3.x; a7 += p3.y;                 \
    } while (0)

    for (int base = s; base < e; base += 64) {
        int cnt = min(64, e - base);
        int idx = (base + lane < e) ? (int)csr[base + lane] : 0;
        int j = 0;
        for (; j + 8 <= cnt; j += 8) {
            int s0 = __shfl(idx, j + eg);
            int s1 = __shfl(idx, j + 4 + eg);
            uint2 v0 = *(const uint2*)(hrow + (size_t)s0 * 128);
            uint2 v1 = *(const uint2*)(hrow + (size_t)s1 * 128);
            ACC8(v0);
            ACC8(v1);
        }
        for (; j + 4 <= cnt; j += 4) {
            int s0 = __shfl(idx, j + eg);
            uint2 v0 = *(const uint2*)(hrow + (size_t)s0 * 128);
            ACC8(v0);
        }
        if (j < cnt) {
            int k = j + eg;
            int sm = __shfl(idx, (k < cnt) ? k : (cnt - 1));
            uint2 v = *(const uint2*)(hrow + (size_t)sm * 128);
            if (k >= cnt) v = make_uint2(0u, 0u);
            ACC8(v);
        }
    }
#undef ACC8

    a0 += __shfl_xor(a0, 16); a0 += __shfl_xor(a0, 32);
    a1 += __shfl_xor(a1, 16); a1 += __shfl_xor(a1, 32);
    a2 += __shfl_xor(a2, 16); a2 += __shfl_xor(a2, 32);
    a3 += __shfl_xor(a3, 16); a3 += __shfl_xor(a3, 32);
    a4 += __shfl_xor(a4, 16); a4 += __shfl_xor(a4, 32);
    a5 += __shfl_xor(a5, 16); a5 += __shfl_xor(a5, 32);
    a6 += __shfl_xor(a6, 16); a6 += __shfl_xor(a6, 32);
    a7 += __shfl_xor(a7, 16); a7 += __shfl_xor(a7, 32);

    unsigned u0 = (unsigned)f2bf(a0) | ((unsigned)f2bf(a1) << 16);
    unsigned u1 = (unsigned)f2bf(a2) | ((unsigned)f2bf(a3) << 16);
    unsigned u2 = (unsigned)f2bf(a4) | ((unsigned)f2bf(a5) << 16);
    unsigned u3 = (unsigned)f2bf(a6) | ((unsigned)f2bf(a7) << 16);
    if (eg == 0)
        *(uint4*)(aggb + (size_t)node * 128 + fb * 8) = make_uint4(u0, u1, u2, u3);
}

// ---------------- SAGE layer GEMM via bf16 MFMA (+fp8-out / +pool) ---------
__global__ __launch_bounds__(256) void k_sage(
    const unsigned short* __restrict__ aggb, const unsigned short* __restrict__ hb,
    const unsigned short* __restrict__ Whi, const unsigned short* __restrict__ Wlo,
    const float* __restrict__ bl, unsigned short* __restrict__ outb,
    unsigned char* __restrict__ out8, const int* __restrict__ batch,
    float* __restrict__ gsum, int n, int do_relu, int do_out8, int do_pool)
{
    __shared__ unsigned short sA[64 * 264];  // 33792 B
    __shared__ float pool[8][128];           // 4 KB (pool fusion)
    int node0 = blockIdx.x * 64;
    int t = threadIdx.x;

    if (do_pool) {
        for (int q = t; q < 1024; q += 256) pool[q >> 7][q & 127] = 0.f;
    }
    for (int q = t; q < 2048; q += 256) {
        int nd = q >> 5;
        int c = q & 31;
        int node = node0 + nd;
        uint4 v = make_uint4(0u, 0u, 0u, 0u);
        if (node < n) {
            const unsigned short* src = (c < 16)
                ? (aggb + (size_t)node * 128 + c * 8)
                : (hb + (size_t)node * 128 + (c - 16) * 8);
            v = *(const uint4*)src;
        }
        *(uint4*)(sA + nd * 264 + c * 8) = v;
    }
    __syncthreads();

    int wv = t >> 6;
    int l = t & 63;
    int quad = l >> 4;
    int mr = l & 15;
    int jbase = wv * 32;

    f32x4 acc[4][2];
#pragma unroll
    for (int mi = 0; mi < 4; ++mi)
#pragma unroll
        for (int jj = 0; jj < 2; ++jj) acc[mi][jj] = (f32x4){0.f, 0.f, 0.f, 0.f};

    for (int s = 0; s < 8; ++s) {
        int koff = s * 32 + quad * 8;
        bf16x8 bh[2], bo[2];
#pragma unroll
        for (int jj = 0; jj < 2; ++jj) {
            size_t wo = (size_t)(jbase + jj * 16 + mr) * 256 + koff;
            bh[jj] = __builtin_bit_cast(bf16x8, *(const uint4*)(Whi + wo));
            bo[jj] = __builtin_bit_cast(bf16x8, *(const uint4*)(Wlo + wo));
        }
#pragma unroll
        for (int mi = 0; mi < 4; ++mi) {
            bf16x8 a = __builtin_bit_cast(
                bf16x8, *(const uint4*)(sA + (mi * 16 + mr) * 264 + koff));
#pragma unroll
            for (int jj = 0; jj < 2; ++jj) {
                acc[mi][jj] = __builtin_amdgcn_mfma_f32_16x16x32_bf16(a, bh[jj], acc[mi][jj], 0, 0, 0);
                acc[mi][jj] = __builtin_amdgcn_mfma_f32_16x16x32_bf16(a, bo[jj], acc[mi][jj], 0, 0, 0);
            }
        }
    }

    int g0 = do_pool ? batch[min(node0, n - 1)] : 0;

#pragma unroll
    for (int mi = 0; mi < 4; ++mi) {
#pragma unroll
        for (int jj = 0; jj < 2; ++jj) {
            int col = jbase + jj * 16 + mr;
            float bias = bl[col];
#pragma unroll
            for (int r = 0; r < 4; ++r) {
                int node = node0 + mi * 16 + quad * 4 + r;
                if (node >= n) continue;
                float v = acc[mi][jj][r] + bias;
                if (do_relu) v = fmaxf(v, 0.f);
                outb[(size_t)node * 128 + col] = f2bf(v);
                if (do_out8) out8[(size_t)node * 128 + col] = f2fp8(v);
                if (do_pool) {
                    int gi = batch[node] - g0;
                    if (gi < 8) atomicAdd(&pool[gi][col], v);
                    else atomicAdd(&gsum[batch[node] * 128 + col], v);
                }
            }
        }
    }

    if (do_pool) {
        __syncthreads();
        for (int q = t; q < 1024; q += 256) {
            int s = q >> 7, c = q & 127;
            float v = pool[s][c];
            if (v != 0.f && g0 + s < 64)
                atomicAdd(&gsum[(g0 + s) * 128 + c], v);
        }
    }
}

// ---------------- final: mean-pool normalize + linear head -----------------
__global__ void k_final(const float* __restrict__ gsum, const int* __restrict__ batch,
                        const float* __restrict__ Wlin, const float* __restrict__ blin,
                        float* __restrict__ out, int n)
{
    int g = blockIdx.x;   // 64
    int o = threadIdx.x;  // 64
    // count via binary search on sorted batch
    int lo = 0, hi = n;
    while (lo < hi) { int m = (lo + hi) >> 1; if (batch[m] < g) lo = m + 1; else hi = m; }
    int lb = lo;
    hi = n;
    while (lo < hi) { int m = (lo + hi) >> 1; if (batch[m] < g + 1) lo = m + 1; else hi = m; }
    float cntf = (float)(lo - lb);
    float inv = 1.f / fmaxf(cntf, 1.f);
    float acc = 0.f;
    for (int k = 0; k < 128; ++k)
        acc += gsum[g * 128 + k] * Wlin[o * 128 + k];
    out[g * 64 + o] = acc * inv + blin[o];
}

extern "C" void kernel_launch(void* const* d_in, const int* in_sizes, int n_in,
                              void* d_out, int out_size, void* d_ws, size_t ws_size,
                              hipStream_t stream) {
    const float* x     = (const float*)d_in[0];
    const int*   ei    = (const int*)d_in[1];
    const int*   batch = (const int*)d_in[2];
    const float* W1l = (const float*)d_in[3];
    const float* b1l = (const float*)d_in[4];
    const float* W1r = (const float*)d_in[5];
    const float* W2l = (const float*)d_in[6];
    const float* b2l = (const float*)d_in[7];
    const float* W2r = (const float*)d_in[8];
    const float* W3l = (const float*)d_in[9];
    const float* b3l = (const float*)d_in[10];
    const float* W3r = (const float*)d_in[11];
    const float* Wlin = (const float*)d_in[12];
    const float* blin = (const float*)d_in[13];

    const int N = in_sizes[2];       // 50000
    const int E = in_sizes[1] / 2;   // 800000
    const int nb = (N + 127) >> 7;   // 391 buckets
    const int epb = (E + BINB - 1) / BINB;  // 5000 edges per bin block

    size_t off = 0;
    auto alloc = [&](size_t bytes) {
        void* p = (char*)d_ws + off;
        off += (bytes + 255) & ~(size_t)255;
        return p;
    };
    int* csr_start = (int*)alloc((size_t)(N + 1) * 4);
    int* cnt_mat   = (int*)alloc((size_t)nb * BINB * 4);
    int* rowloc    = (int*)alloc((size_t)nb * BINB * 4);
    int* btot      = (int*)alloc((size_t)NBMAX * 4);
    int* bbase     = (int*)alloc((size_t)NBMAX * 4);
    unsigned short* csr_src = (unsigned short*)alloc((size_t)E * 2);
    unsigned short* x_bf   = (unsigned short*)alloc((size_t)N * 128 * 2);
    unsigned short* hA     = (unsigned short*)alloc((size_t)N * 128 * 2);
    unsigned short* hB     = (unsigned short*)alloc((size_t)N * 128 * 2);
    unsigned short* agg_bf = (unsigned short*)alloc((size_t)N * 128 * 2);
    unsigned char*  h_f8   = (unsigned char*)alloc((size_t)N * 128);
    unsigned short* Whi = (unsigned short*)alloc(3 * 128 * 256 * 2);
    unsigned short* Wlo = (unsigned short*)alloc(3 * 128 * 256 * 2);
    float* gsum = (float*)alloc((size_t)64 * 128 * 4);
    (void)ws_size;

    // binned aliases agg_bf: consumed by k_fillfine2 before first k_agg write.
    unsigned* binned = (unsigned*)agg_bf;

    hipMemsetAsync(gsum, 0, (size_t)64 * 128 * 4, stream);

    // --- CSR build (5 launches) ---
    k_bincount<<<BINB, 256, 0, stream>>>(ei + E, cnt_mat, E, nb, epb);
    k_mrowscan<<<nb, 256, 0, stream>>>(cnt_mat, rowloc, btot);
    k_scan2b<<<1, 256, 0, stream>>>(btot, bbase, nb, csr_start + N);
    k_binscatter<<<BINB, 256, 0, stream>>>(ei, rowloc, bbase, binned, E, nb, epb);
    k_fillfine2<<<nb, 256, 0, stream>>>(binned, bbase, csr_start, csr_src, E, nb, N);

    // --- casts (1 launch) ---
    int n8 = N * 128 / 8;             // 800000
    int nxblk = (n8 + 255) / 256;     // 3125
    k_cast_all<<<nxblk + 3 * 128, 256, 0, stream>>>(
        x, x_bf, h_f8, n8, nxblk, W1l, W1r, W2l, W2r, W3l, W3r, Whi, Wlo);

    int agg_grid = (N + 3) / 4;
    int sage_grid = (N + 63) / 64;

    // Layer 1: gather fp8(x) -> agg; GEMM -> hA (relu) + fp8 out
    k_agg<<<agg_grid, 256, 0, stream>>>(h_f8, csr_start, csr_src, agg_bf, N);
    k_sage<<<sage_grid, 256, 0, stream>>>(agg_bf, x_bf, Whi, Wlo, b1l,
                                          hA, h_f8, batch, gsum, N, 1, 1, 0);
    // Layer 2
    k_agg<<<agg_grid, 256, 0, stream>>>(h_f8, csr_start, csr_src, agg_bf, N);
    k_sage<<<sage_grid, 256, 0, stream>>>(agg_bf, hA, Whi + 32768, Wlo + 32768, b2l,
                                          hB, h_f8, batch, gsum, N, 1, 1, 0);
    // Layer 3 (no relu, pool fused)
    k_agg<<<agg_grid, 256, 0, stream>>>(h_f8, csr_start, csr_src, agg_bf, N);
    k_sage<<<sage_grid, 256, 0, stream>>>(agg_bf, hB, Whi + 65536, Wlo + 65536, b3l,
                                          hA, h_f8, batch, gsum, N, 0, 0, 1);

    // Head
    k_final<<<64, 64, 0, stream>>>(gsum, batch, Wlin, blin, (float*)d_out, N);
}

// Round 11
// 296.399 us; speedup vs baseline: 1.0950x; 1.0950x over previous
//
#include <hip/hip_runtime.h>

// HierarchicalGraphSAGE bf16-MFMA version, R11.
// N=50000, E=800000, D=128, OUT=64, G=64.
//
//  R11 vs R10: weights pre-packed into MFMA-fragment order.
//  R10 profile showed k_sage = 62.8us with ALL pipes idle (Mfma 3.7%, VALU 6%,
//  HBM 5.3%): the weight loads were 512B-strided across lanes -> 64 cache
//  lines per wave load, 2048 scattered L2 requests per wave. Packed layout
//  [wv][s][jj][lane][8] makes every weight load a coalesced 1KB wave load.
//  Math is bit-identical; only the address map changed.

typedef __bf16 bf16x8 __attribute__((ext_vector_type(8)));
typedef float f32x4 __attribute__((ext_vector_type(4)));
typedef float f32x2 __attribute__((ext_vector_type(2)));

#define BINB 160          // binning blocks
#define NBMAX 512         // max buckets (N <= 65536)

static __device__ __forceinline__ float bf2f(unsigned short u) {
    union { unsigned u; float f; } c; c.u = (unsigned)u << 16; return c.f;
}
static __device__ __forceinline__ unsigned short f2bf(float f) {
    unsigned u = __builtin_bit_cast(unsigned, f);
    return (unsigned short)((u + 0x7fffu + ((u >> 16) & 1u)) >> 16);
}
static __device__ __forceinline__ uint2 pk8_fp8(const float* f) {
    int lo = 0, hi = 0;
    lo = __builtin_amdgcn_cvt_pk_fp8_f32(f[0], f[1], lo, false);
    lo = __builtin_amdgcn_cvt_pk_fp8_f32(f[2], f[3], lo, true);
    hi = __builtin_amdgcn_cvt_pk_fp8_f32(f[4], f[5], hi, false);
    hi = __builtin_amdgcn_cvt_pk_fp8_f32(f[6], f[7], hi, true);
    return make_uint2((unsigned)lo, (unsigned)hi);
}
static __device__ __forceinline__ unsigned char f2fp8(float v) {
    return (unsigned char)(__builtin_amdgcn_cvt_pk_fp8_f32(v, v, 0, false) & 0xff);
}

// ---------------- bucket counting sort ----------------
__global__ __launch_bounds__(256) void k_bincount(
    const int* __restrict__ dst, int* __restrict__ cnt_mat, int E, int nb, int epb)
{
    __shared__ int lc[NBMAX];
    for (int i = threadIdx.x; i < nb; i += 256) lc[i] = 0;
    __syncthreads();
    int b0 = blockIdx.x * epb;
    int b1 = min(b0 + epb, E);
    for (int i = b0 + threadIdx.x; i < b1; i += 256)
        atomicAdd(&lc[dst[i] >> 7], 1);
    __syncthreads();
    for (int i = threadIdx.x; i < nb; i += 256)
        cnt_mat[i * BINB + blockIdx.x] = lc[i];
}

// Per-bucket: exclusive scan of its BINB-entry row; emit bucket total.
__global__ __launch_bounds__(256) void k_mrowscan(
    const int* __restrict__ cnt_mat, int* __restrict__ rowloc, int* __restrict__ btot)
{
    __shared__ int s[256];
    int b = blockIdx.x;
    int t = threadIdx.x;
    int v = (t < BINB) ? cnt_mat[b * BINB + t] : 0;
    s[t] = v;
    __syncthreads();
#pragma unroll
    for (int off = 1; off < 256; off <<= 1) {
        int u = (t >= off) ? s[t - off] : 0;
        __syncthreads();
        s[t] += u;
        __syncthreads();
    }
    if (t < BINB) rowloc[b * BINB + t] = s[t] - v;
    if (t == 255) btot[b] = s[255];
}

// Single block: exclusive scan of nb bucket totals -> bbase; total -> *total_out.
__global__ __launch_bounds__(256) void k_scan2b(
    const int* __restrict__ btot, int* __restrict__ bbase, int nb, int* __restrict__ total_out)
{
    __shared__ int s[256];
    int t = threadIdx.x;
    int per = (nb + 255) / 256;
    int s0 = t * per, e0 = min(s0 + per, nb);
    int sum = 0;
    for (int i = s0; i < e0; ++i) sum += btot[i];
    s[t] = sum;
    __syncthreads();
#pragma unroll
    for (int off = 1; off < 256; off <<= 1) {
        int u = (t >= off) ? s[t - off] : 0;
        __syncthreads();
        s[t] += u;
        __syncthreads();
    }
    int run = s[t] - sum;
    for (int i = s0; i < e0; ++i) { bbase[i] = run; run += btot[i]; }
    if (t == 255) *total_out = s[255];
}

__global__ __launch_bounds__(256) void k_binscatter(
    const int* __restrict__ ei, const int* __restrict__ rowloc, const int* __restrict__ bbase,
    unsigned* __restrict__ binned, int E, int nb, int epb)
{
    __shared__ int lofs[NBMAX];
    __shared__ int lcnt[NBMAX];
    for (int i = threadIdx.x; i < nb; i += 256) {
        lofs[i] = rowloc[i * BINB + blockIdx.x] + bbase[i];
        lcnt[i] = 0;
    }
    __syncthreads();
    int b0 = blockIdx.x * epb;
    int b1 = min(b0 + epb, E);
    for (int i = b0 + threadIdx.x; i < b1; i += 256) {
        int s = ei[i];
        int d = ei[E + i];
        int b = d >> 7;
        int r = atomicAdd(&lcnt[b], 1);
        binned[lofs[b] + r] = (unsigned)s | ((unsigned)(d & 127) << 16);
    }
}

// Per-bucket: node hist -> local scan -> starts[] -> fine scatter. All in LDS.
__global__ __launch_bounds__(256) void k_fillfine2(
    const unsigned* __restrict__ binned, const int* __restrict__ bbase,
    int* __restrict__ starts, unsigned short* __restrict__ csr_src,
    int E, int nb, int n)
{
    __shared__ int lc[128];
    __shared__ int lpos[128];
    int b = blockIdx.x;
    int t = threadIdx.x;
    int node0 = b << 7;
    int bs = bbase[b];
    int be = (b == nb - 1) ? E : bbase[b + 1];
    if (t < 128) lc[t] = 0;
    __syncthreads();
    for (int i = bs + t; i < be; i += 256)
        atomicAdd(&lc[(binned[i] >> 16) & 127], 1);
    __syncthreads();
    int v = (t < 128) ? lc[t] : 0;
    if (t < 128) lpos[t] = v;
    __syncthreads();
#pragma unroll
    for (int off = 1; off < 128; off <<= 1) {
        int u = (t >= off && t < 128) ? lpos[t - off] : 0;
        __syncthreads();
        if (t < 128) lpos[t] += u;
        __syncthreads();
    }
    int excl = (t < 128) ? (lpos[t] - v) : 0;
    __syncthreads();
    if (t < 128) {
        int node = node0 + t;
        if (node < n) starts[node] = bs + excl;
        lpos[t] = bs + excl;
    }
    if (b == nb - 1 && t == 0) starts[n] = E;
    __syncthreads();
    for (int i = bs + t; i < be; i += 256) {
        unsigned e = binned[i];
        int slot = atomicAdd(&lpos[(e >> 16) & 127], 1);
        csr_src[slot] = (unsigned short)(e & 0xffffu);
    }
}

// ---------------- casts: x -> bf16+fp8; weights -> MFMA-fragment pack ------
// Packed layout per layer (32768 ushorts): frag = (wv*8+s)*2+jj, then
// [lane][8] with lane = quad*16+mr; element e = k&7.
// Row j = wv*32 + jj*16 + mr; col k = s*32 + quad*8 + e.
__global__ __launch_bounds__(256) void k_cast_all(
    const float* __restrict__ x, unsigned short* __restrict__ xb,
    unsigned char* __restrict__ x8, int n8, int nxblk,
    const float* __restrict__ W1l, const float* __restrict__ W1r,
    const float* __restrict__ W2l, const float* __restrict__ W2r,
    const float* __restrict__ W3l, const float* __restrict__ W3r,
    unsigned short* __restrict__ Whi, unsigned short* __restrict__ Wlo)
{
    int bid = blockIdx.x;
    if (bid < nxblk) {
        int i = bid * 256 + threadIdx.x;
        if (i >= n8) return;
        float f[8];
        *(float4*)(f + 0) = *(const float4*)(x + (size_t)i * 8);
        *(float4*)(f + 4) = *(const float4*)(x + (size_t)i * 8 + 4);
        ushort4 oa, ob;
        oa.x = f2bf(f[0]); oa.y = f2bf(f[1]); oa.z = f2bf(f[2]); oa.w = f2bf(f[3]);
        ob.x = f2bf(f[4]); ob.y = f2bf(f[5]); ob.z = f2bf(f[6]); ob.w = f2bf(f[7]);
        *(ushort4*)(xb + (size_t)i * 8) = oa;
        *(ushort4*)(xb + (size_t)i * 8 + 4) = ob;
        *(uint2*)(x8 + (size_t)i * 8) = pk8_fp8(f);
    } else {
        int wb = bid - nxblk;          // 0..383
        int layer = wb >> 7;
        int j = wb & 127;              // output row (col of C)
        int k = threadIdx.x;           // 0..255
        const float* Wl = (layer == 0) ? W1l : (layer == 1) ? W2l : W3l;
        const float* Wr = (layer == 0) ? W1r : (layer == 1) ? W2r : W3r;
        float w = (k < 128) ? Wl[j * 128 + k] : Wr[j * 128 + k - 128];
        unsigned short hi = f2bf(w);
        float lo = w - bf2f(hi);
        int wv = j >> 5, jj = (j >> 4) & 1, mr = j & 15;
        int s = k >> 5, quad = (k >> 3) & 3, e = k & 7;
        int lane = quad * 16 + mr;
        size_t o = (size_t)layer * 32768
                 + ((size_t)(((wv * 8 + s) * 2 + jj)) * 64 + lane) * 8 + e;
        Whi[o] = hi;
        Wlo[o] = f2bf(lo);
    }
}

// ---------------- aggregate: wave/node, fp8 rows, 4 edges per wave load ----
__global__ __launch_bounds__(256) void k_agg(
    const unsigned char* __restrict__ h8, const int* __restrict__ starts,
    const unsigned short* __restrict__ csr, unsigned short* __restrict__ aggb, int n)
{
    int node = blockIdx.x * 4 + (threadIdx.x >> 6);
    int lane = threadIdx.x & 63;
    if (node >= n) return;
    int eg = lane >> 4;
    int fb = lane & 15;
    const unsigned char* hrow = h8 + fb * 8;
    int s = starts[node], e = starts[node + 1];
    float a0 = 0.f, a1 = 0.f, a2 = 0.f, a3 = 0.f,
          a4 = 0.f, a5 = 0.f, a6 = 0.f, a7 = 0.f;

#define ACC8(v)                                                         \
    do {                                                                \
        f32x2 p0 = __builtin_amdgcn_cvt_pk_f32_fp8((v).x, false);       \
        f32x2 p1 = __builtin_amdgcn_cvt_pk_f32_fp8((v).x, true);        \
        f32x2 p2 = __builtin_amdgcn_cvt_pk_f32_fp8((v).y, false);       \
        f32x2 p3 = __builtin_amdgcn_cvt_pk_f32_fp8((v).y, true);        \
        a0 += p0.x; a1 += p0.y; a2 += p1.x; a3 += p1.y;                 \
        a4 += p2.x; a5 += p2.y; a6 += p3.x; a7 += p3.y;                 \
    } while (0)

    for (int base = s; base < e; base += 64) {
        int cnt = min(64, e - base);
        int idx = (base + lane < e) ? (int)csr[base + lane] : 0;
        int j = 0;
        for (; j + 8 <= cnt; j += 8) {
            int s0 = __shfl(idx, j + eg);
            int s1 = __shfl(idx, j + 4 + eg);
            uint2 v0 = *(const uint2*)(hrow + (size_t)s0 * 128);
            uint2 v1 = *(const uint2*)(hrow + (size_t)s1 * 128);
            ACC8(v0);
            ACC8(v1);
        }
        for (; j + 4 <= cnt; j += 4) {
            int s0 = __shfl(idx, j + eg);
            uint2 v0 = *(const uint2*)(hrow + (size_t)s0 * 128);
            ACC8(v0);
        }
        if (j < cnt) {
            int k = j + eg;
            int sm = __shfl(idx, (k < cnt) ? k : (cnt - 1));
            uint2 v = *(const uint2*)(hrow + (size_t)sm * 128);
            if (k >= cnt) v = make_uint2(0u, 0u);
            ACC8(v);
        }
    }
#undef ACC8

    a0 += __shfl_xor(a0, 16); a0 += __shfl_xor(a0, 32);
    a1 += __shfl_xor(a1, 16); a1 += __shfl_xor(a1, 32);
    a2 += __shfl_xor(a2, 16); a2 += __shfl_xor(a2, 32);
    a3 += __shfl_xor(a3, 16); a3 += __shfl_xor(a3, 32);
    a4 += __shfl_xor(a4, 16); a4 += __shfl_xor(a4, 32);
    a5 += __shfl_xor(a5, 16); a5 += __shfl_xor(a5, 32);
    a6 += __shfl_xor(a6, 16); a6 += __shfl_xor(a6, 32);
    a7 += __shfl_xor(a7, 16); a7 += __shfl_xor(a7, 32);

    unsigned u0 = (unsigned)f2bf(a0) | ((unsigned)f2bf(a1) << 16);
    unsigned u1 = (unsigned)f2bf(a2) | ((unsigned)f2bf(a3) << 16);
    unsigned u2 = (unsigned)f2bf(a4) | ((unsigned)f2bf(a5) << 16);
    unsigned u3 = (unsigned)f2bf(a6) | ((unsigned)f2bf(a7) << 16);
    if (eg == 0)
        *(uint4*)(aggb + (size_t)node * 128 + fb * 8) = make_uint4(u0, u1, u2, u3);
}

// ---------------- SAGE layer GEMM via bf16 MFMA (+fp8-out / +pool) ---------
// Weight loads now hit the packed layout: frag (wv,s,jj) at
// Wpk + frag*512 ushorts, lane-contiguous 16B -> coalesced 1KB wave loads.
__global__ __launch_bounds__(256) void k_sage(
    const unsigned short* __restrict__ aggb, const unsigned short* __restrict__ hb,
    const unsigned short* __restrict__ Whi, const unsigned short* __restrict__ Wlo,
    const float* __restrict__ bl, unsigned short* __restrict__ outb,
    unsigned char* __restrict__ out8, const int* __restrict__ batch,
    float* __restrict__ gsum, int n, int do_relu, int do_out8, int do_pool)
{
    __shared__ unsigned short sA[64 * 264];  // 33792 B
    __shared__ float pool[8][128];           // 4 KB (pool fusion)
    int node0 = blockIdx.x * 64;
    int t = threadIdx.x;

    if (do_pool) {
        for (int q = t; q < 1024; q += 256) pool[q >> 7][q & 127] = 0.f;
    }
    for (int q = t; q < 2048; q += 256) {
        int nd = q >> 5;
        int c = q & 31;
        int node = node0 + nd;
        uint4 v = make_uint4(0u, 0u, 0u, 0u);
        if (node < n) {
            const unsigned short* src = (c < 16)
                ? (aggb + (size_t)node * 128 + c * 8)
                : (hb + (size_t)node * 128 + (c - 16) * 8);
            v = *(const uint4*)src;
        }
        *(uint4*)(sA + nd * 264 + c * 8) = v;
    }
    __syncthreads();

    int wv = t >> 6;
    int l = t & 63;
    int quad = l >> 4;
    int mr = l & 15;
    int jbase = wv * 32;

    f32x4 acc[4][2];
#pragma unroll
    for (int mi = 0; mi < 4; ++mi)
#pragma unroll
        for (int jj = 0; jj < 2; ++jj) acc[mi][jj] = (f32x4){0.f, 0.f, 0.f, 0.f};

    const unsigned short* wphi = Whi + ((size_t)wv * 8 * 2) * 512 + (size_t)l * 8;
    const unsigned short* wplo = Wlo + ((size_t)wv * 8 * 2) * 512 + (size_t)l * 8;

    for (int s = 0; s < 8; ++s) {
        int koff = s * 32 + quad * 8;
        bf16x8 bh[2], bo[2];
#pragma unroll
        for (int jj = 0; jj < 2; ++jj) {
            size_t fo = (size_t)(s * 2 + jj) * 512;
            bh[jj] = __builtin_bit_cast(bf16x8, *(const uint4*)(wphi + fo));
            bo[jj] = __builtin_bit_cast(bf16x8, *(const uint4*)(wplo + fo));
        }
#pragma unroll
        for (int mi = 0; mi < 4; ++mi) {
            bf16x8 a = __builtin_bit_cast(
                bf16x8, *(const uint4*)(sA + (mi * 16 + mr) * 264 + koff));
#pragma unroll
            for (int jj = 0; jj < 2; ++jj) {
                acc[mi][jj] = __builtin_amdgcn_mfma_f32_16x16x32_bf16(a, bh[jj], acc[mi][jj], 0, 0, 0);
                acc[mi][jj] = __builtin_amdgcn_mfma_f32_16x16x32_bf16(a, bo[jj], acc[mi][jj], 0, 0, 0);
            }
        }
    }

    int g0 = do_pool ? batch[min(node0, n - 1)] : 0;

#pragma unroll
    for (int mi = 0; mi < 4; ++mi) {
#pragma unroll
        for (int jj = 0; jj < 2; ++jj) {
            int col = jbase + jj * 16 + mr;
            float bias = bl[col];
#pragma unroll
            for (int r = 0; r < 4; ++r) {
                int node = node0 + mi * 16 + quad * 4 + r;
                if (node >= n) continue;
                float v = acc[mi][jj][r] + bias;
                if (do_relu) v = fmaxf(v, 0.f);
                outb[(size_t)node * 128 + col] = f2bf(v);
                if (do_out8) out8[(size_t)node * 128 + col] = f2fp8(v);
                if (do_pool) {
                    int gi = batch[node] - g0;
                    if (gi < 8) atomicAdd(&pool[gi][col], v);
                    else atomicAdd(&gsum[batch[node] * 128 + col], v);
                }
            }
        }
    }

    if (do_pool) {
        __syncthreads();
        for (int q = t; q < 1024; q += 256) {
            int s = q >> 7, c = q & 127;
            float v = pool[s][c];
            if (v != 0.f && g0 + s < 64)
                atomicAdd(&gsum[(g0 + s) * 128 + c], v);
        }
    }
}

// ---------------- final: mean-pool normalize + linear head -----------------
__global__ void k_final(const float* __restrict__ gsum, const int* __restrict__ batch,
                        const float* __restrict__ Wlin, const float* __restrict__ blin,
                        float* __restrict__ out, int n)
{
    int g = blockIdx.x;   // 64
    int o = threadIdx.x;  // 64
    int lo = 0, hi = n;
    while (lo < hi) { int m = (lo + hi) >> 1; if (batch[m] < g) lo = m + 1; else hi = m; }
    int lb = lo;
    hi = n;
    while (lo < hi) { int m = (lo + hi) >> 1; if (batch[m] < g + 1) lo = m + 1; else hi = m; }
    float cntf = (float)(lo - lb);
    float inv = 1.f / fmaxf(cntf, 1.f);
    float acc = 0.f;
    for (int k = 0; k < 128; ++k)
        acc += gsum[g * 128 + k] * Wlin[o * 128 + k];
    out[g * 64 + o] = acc * inv + blin[o];
}

extern "C" void kernel_launch(void* const* d_in, const int* in_sizes, int n_in,
                              void* d_out, int out_size, void* d_ws, size_t ws_size,
                              hipStream_t stream) {
    const float* x     = (const float*)d_in[0];
    const int*   ei    = (const int*)d_in[1];
    const int*   batch = (const int*)d_in[2];
    const float* W1l = (const float*)d_in[3];
    const float* b1l = (const float*)d_in[4];
    const float* W1r = (const float*)d_in[5];
    const float* W2l = (const float*)d_in[6];
    const float* b2l = (const float*)d_in[7];
    const float* W2r = (const float*)d_in[8];
    const float* W3l = (const float*)d_in[9];
    const float* b3l = (const float*)d_in[10];
    const float* W3r = (const float*)d_in[11];
    const float* Wlin = (const float*)d_in[12];
    const float* blin = (const float*)d_in[13];

    const int N = in_sizes[2];       // 50000
    const int E = in_sizes[1] / 2;   // 800000
    const int nb = (N + 127) >> 7;   // 391 buckets
    const int epb = (E + BINB - 1) / BINB;  // 5000 edges per bin block

    size_t off = 0;
    auto alloc = [&](size_t bytes) {
        void* p = (char*)d_ws + off;
        off += (bytes + 255) & ~(size_t)255;
        return p;
    };
    int* csr_start = (int*)alloc((size_t)(N + 1) * 4);
    int* cnt_mat   = (int*)alloc((size_t)nb * BINB * 4);
    int* rowloc    = (int*)alloc((size_t)nb * BINB * 4);
    int* btot      = (int*)alloc((size_t)NBMAX * 4);
    int* bbase     = (int*)alloc((size_t)NBMAX * 4);
    unsigned short* csr_src = (unsigned short*)alloc((size_t)E * 2);
    unsigned short* x_bf   = (unsigned short*)alloc((size_t)N * 128 * 2);
    unsigned short* hA     = (unsigned short*)alloc((size_t)N * 128 * 2);
    unsigned short* hB     = (unsigned short*)alloc((size_t)N * 128 * 2);
    unsigned short* agg_bf = (unsigned short*)alloc((size_t)N * 128 * 2);
    unsigned char*  h_f8   = (unsigned char*)alloc((size_t)N * 128);
    unsigned short* Whi = (unsigned short*)alloc(3 * 128 * 256 * 2);
    unsigned short* Wlo = (unsigned short*)alloc(3 * 128 * 256 * 2);
    float* gsum = (float*)alloc((size_t)64 * 128 * 4);
    (void)ws_size;

    // binned aliases agg_bf: consumed by k_fillfine2 before first k_agg write.
    unsigned* binned = (unsigned*)agg_bf;

    hipMemsetAsync(gsum, 0, (size_t)64 * 128 * 4, stream);

    // --- CSR build (5 launches) ---
    k_bincount<<<BINB, 256, 0, stream>>>(ei + E, cnt_mat, E, nb, epb);
    k_mrowscan<<<nb, 256, 0, stream>>>(cnt_mat, rowloc, btot);
    k_scan2b<<<1, 256, 0, stream>>>(btot, bbase, nb, csr_start + N);
    k_binscatter<<<BINB, 256, 0, stream>>>(ei, rowloc, bbase, binned, E, nb, epb);
    k_fillfine2<<<nb, 256, 0, stream>>>(binned, bbase, csr_start, csr_src, E, nb, N);

    // --- casts (1 launch) ---
    int n8 = N * 128 / 8;             // 800000
    int nxblk = (n8 + 255) / 256;     // 3125
    k_cast_all<<<nxblk + 3 * 128, 256, 0, stream>>>(
        x, x_bf, h_f8, n8, nxblk, W1l, W1r, W2l, W2r, W3l, W3r, Whi, Wlo);

    int agg_grid = (N + 3) / 4;
    int sage_grid = (N + 63) / 64;

    // Layer 1: gather fp8(x) -> agg; GEMM -> hA (relu) + fp8 out
    k_agg<<<agg_grid, 256, 0, stream>>>(h_f8, csr_start, csr_src, agg_bf, N);
    k_sage<<<sage_grid, 256, 0, stream>>>(agg_bf, x_bf, Whi, Wlo, b1l,
                                          hA, h_f8, batch, gsum, N, 1, 1, 0);
    // Layer 2
    k_agg<<<agg_grid, 256, 0, stream>>>(h_f8, csr_start, csr_src, agg_bf, N);
    k_sage<<<sage_grid, 256, 0, stream>>>(agg_bf, hA, Whi + 32768, Wlo + 32768, b2l,
                                          hB, h_f8, batch, gsum, N, 1, 1, 0);
    // Layer 3 (no relu, pool fused)
    k_agg<<<agg_grid, 256, 0, stream>>>(h_f8, csr_start, csr_src, agg_bf, N);
    k_sage<<<sage_grid, 256, 0, stream>>>(agg_bf, hB, Whi + 65536, Wlo + 65536, b3l,
                                          hA, h_f8, batch, gsum, N, 0, 0, 1);

    // Head
    k_final<<<64, 64, 0, stream>>>(gsum, batch, Wlin, blin, (float*)d_out, N);
}